// Round 7
// baseline (744.851 us; speedup 1.0000x reference)
//
#include <hip/hip_runtime.h>
#include <hip/hip_bf16.h>

#define N_NODES 50000
#define N_EDGES 1600000
#define HEADS 8
#define HD 32
#define FIN 256
#define HID 256

typedef unsigned short u16;
typedef unsigned int u32;
typedef unsigned char u8;

typedef short s8v __attribute__((ext_vector_type(8)));   // 8 bf16 (4 VGPRs)
typedef float f4v __attribute__((ext_vector_type(4)));   // 4 fp32 acc
typedef float f2v __attribute__((ext_vector_type(2)));

__device__ __forceinline__ float bf2f(u16 v) {
  union { u32 u; float f; } c; c.u = ((u32)v) << 16; return c.f;
}
__device__ __forceinline__ u16 f2bf(float f) {
  union { u32 u; float f; } c; c.f = f;
  u32 u = c.u;
  return (u16)((u + 0x7FFFu + ((u >> 16) & 1u)) >> 16);  // RNE
}
__device__ __forceinline__ u32 pk2(float lo, float hi) {
  return (u32)f2bf(lo) | ((u32)f2bf(hi) << 16);
}

// ---------------- W transpose prep: Wt_g[h*32+d][k] bf16 --------------------
__global__ __launch_bounds__(256) void k_wprep(const float* __restrict__ W,
                                               u16* __restrict__ Wt_g) {
  int idx = blockIdx.x * 256 + threadIdx.x;   // 16384 threads, one float4 each
  int d4 = idx & 7;                            // 4-d group
  int hk = idx >> 3;                           // h*256 + k
  int h = hk >> 8, k = hk & 255;
  float4 w = *(const float4*)&W[hk * 32 + d4 * 4];
  int colb = h * 32 + d4 * 4;
  Wt_g[(colb + 0) * 256 + k] = f2bf(w.x);
  Wt_g[(colb + 1) * 256 + k] = f2bf(w.y);
  Wt_g[(colb + 2) * 256 + k] = f2bf(w.z);
  Wt_g[(colb + 3) * 256 + k] = f2bf(w.w);
}

// ---------------- MFMA GEMM + fused attn projections ------------------------
__global__ __launch_bounds__(256) void k_gemm(
    const float* __restrict__ X, const u16* __restrict__ Wt_g,
    const float* __restrict__ bw, const float* __restrict__ A,
    u16* __restrict__ Hb, float* __restrict__ si, float* __restrict__ sj) {
  __shared__ __align__(16) u16 Xs[128 * 40];  // [row][k] stride 40
  __shared__ __align__(16) u16 Wt[128 * 40];  // [col][k] stride 40

  const int t = threadIdx.x;
  const int m0 = (blockIdx.x >> 1) * 128;
  const int n0 = (blockIdx.x & 1) * 128;
  const int w = t >> 6;
  const int lane = t & 63;
  const int l15 = lane & 15;
  const int quad = lane >> 4;
  const int wm = (w >> 1) * 64;
  const int wn = (w & 1) * 64;

  f4v acc[4][4];
#pragma unroll
  for (int i = 0; i < 4; i++)
#pragma unroll
    for (int j = 0; j < 4; j++) acc[i][j] = (f4v){0.f, 0.f, 0.f, 0.f};

  const int nl = t & 127;          // local col
  const int half = t >> 7;         // k half: 16 k's

  for (int k0 = 0; k0 < FIN; k0 += 32) {
#pragma unroll
    for (int p = 0; p < 4; p++) {
      int row = p * 32 + (t >> 3);
      int f4 = t & 7;
      int node = m0 + row;
      float4 xv = make_float4(0.f, 0.f, 0.f, 0.f);
      if (node < N_NODES) xv = *(const float4*)&X[node * FIN + k0 + f4 * 4];
      u32* dst = (u32*)&Xs[row * 40 + f4 * 4];
      dst[0] = pk2(xv.x, xv.y);
      dst[1] = pk2(xv.z, xv.w);
    }
    {
      const u16* wp = Wt_g + (n0 + nl) * 256 + k0 + half * 16;
      *(s8v*)&Wt[nl * 40 + half * 16]     = *(const s8v*)wp;
      *(s8v*)&Wt[nl * 40 + half * 16 + 8] = *(const s8v*)(wp + 8);
    }
    __syncthreads();
    s8v af[4], bf[4];
#pragma unroll
    for (int mi = 0; mi < 4; mi++)
      af[mi] = *(const s8v*)&Xs[(wm + mi * 16 + l15) * 40 + quad * 8];
#pragma unroll
    for (int ni = 0; ni < 4; ni++)
      bf[ni] = *(const s8v*)&Wt[(wn + ni * 16 + l15) * 40 + quad * 8];
#pragma unroll
    for (int mi = 0; mi < 4; mi++)
#pragma unroll
      for (int ni = 0; ni < 4; ni++)
        acc[mi][ni] = __builtin_amdgcn_mfma_f32_16x16x32_bf16(af[mi], bf[ni], acc[mi][ni], 0, 0, 0);
    __syncthreads();
  }

  const int head0 = (n0 + wn) >> 5;
  const int head1 = head0 + 1;
  float c1a0 = A[head0 * 64 + l15],      c1a1 = A[head0 * 64 + 16 + l15];
  float c2a0 = A[head0 * 64 + 32 + l15], c2a1 = A[head0 * 64 + 48 + l15];
  float c1b0 = A[head1 * 64 + l15],      c1b1 = A[head1 * 64 + 16 + l15];
  float c2b0 = A[head1 * 64 + 32 + l15], c2b1 = A[head1 * 64 + 48 + l15];

#pragma unroll
  for (int mi = 0; mi < 4; mi++) {
#pragma unroll
    for (int ni = 0; ni < 4; ni++) {
      float b = bw[n0 + wn + ni * 16 + l15];
#pragma unroll
      for (int r = 0; r < 4; r++) acc[mi][ni][r] += b;
    }
    const int rbase = m0 + wm + mi * 16 + quad * 4;
#pragma unroll
    for (int r = 0; r < 4; r++) {
      int node = rbase + r;
      if (node < N_NODES) {
#pragma unroll
        for (int ni = 0; ni < 4; ni++) {
          int col = n0 + wn + ni * 16 + l15;
          Hb[node * HID + col] = f2bf(acc[mi][ni][r]);
        }
      }
    }
    float s1a[4], s2a[4], s1b[4], s2b[4];
#pragma unroll
    for (int r = 0; r < 4; r++) {
      s1a[r] = acc[mi][0][r] * c1a0 + acc[mi][1][r] * c1a1;
      s2a[r] = acc[mi][0][r] * c2a0 + acc[mi][1][r] * c2a1;
      s1b[r] = acc[mi][2][r] * c1b0 + acc[mi][3][r] * c1b1;
      s2b[r] = acc[mi][2][r] * c2b0 + acc[mi][3][r] * c2b1;
    }
#pragma unroll
    for (int off = 1; off <= 8; off <<= 1) {
#pragma unroll
      for (int r = 0; r < 4; r++) {
        s1a[r] += __shfl_xor(s1a[r], off);
        s2a[r] += __shfl_xor(s2a[r], off);
        s1b[r] += __shfl_xor(s1b[r], off);
        s2b[r] += __shfl_xor(s2b[r], off);
      }
    }
    if (l15 == 0) {
#pragma unroll
      for (int r = 0; r < 4; r++) {
        int node = rbase + r;
        if (node < N_NODES) {
          si[node * HEADS + head0] = s1a[r];
          sj[node * HEADS + head0] = s2a[r];
          si[node * HEADS + head1] = s1b[r];
          sj[node * HEADS + head1] = s2b[r];
        }
      }
    }
  }
}

// ---------------- bf16 H -> fp8 e4m3 Hq (gather payload) --------------------
__global__ __launch_bounds__(256) void k_cvt(const u16* __restrict__ Hb,
                                             u8* __restrict__ Hq) {
  int idx = blockIdx.x * 256 + threadIdx.x;    // 8 elems per thread
  const u32* p = (const u32*)Hb + (size_t)idx * 4;
  u32 w0 = p[0], w1 = p[1], w2 = p[2], w3 = p[3];
  float f0 = bf2f((u16)w0), f1 = bf2f((u16)(w0 >> 16));
  float f2 = bf2f((u16)w1), f3 = bf2f((u16)(w1 >> 16));
  float f4 = bf2f((u16)w2), f5 = bf2f((u16)(w2 >> 16));
  float f6 = bf2f((u16)w3), f7 = bf2f((u16)(w3 >> 16));
  u32 qa = __builtin_amdgcn_cvt_pk_fp8_f32(f0, f1, 0, false);
  qa = __builtin_amdgcn_cvt_pk_fp8_f32(f2, f3, qa, true);
  u32 qb = __builtin_amdgcn_cvt_pk_fp8_f32(f4, f5, 0, false);
  qb = __builtin_amdgcn_cvt_pk_fp8_f32(f6, f7, qb, true);
  u32* q = (u32*)Hq + (size_t)idx * 2;
  q[0] = qa; q[1] = qb;
}

// ---------------- counting sort of edges by target ----------------
__global__ void k_hist(const int* __restrict__ tgt, int* __restrict__ cnt) {
  int e = blockIdx.x * 256 + threadIdx.x;
  if (e < N_EDGES) atomicAdd(&cnt[tgt[e]], 1);
}

__global__ __launch_bounds__(256) void k_scan1(const int* __restrict__ cnt,
    int* __restrict__ excl, int* __restrict__ bsum) {
  __shared__ int s[256];
  const int t = threadIdx.x;
  const int i = blockIdx.x * 256 + t;
  int v = (i < N_NODES) ? cnt[i] : 0;
  s[t] = v;
  __syncthreads();
  int x = v;
  for (int off = 1; off < 256; off <<= 1) {
    int y = (t >= off) ? s[t - off] : 0;
    __syncthreads();
    x += y;
    s[t] = x;
    __syncthreads();
  }
  if (i < N_NODES) excl[i] = x - v;
  if (t == 255) bsum[blockIdx.x] = x;
}

__global__ __launch_bounds__(256) void k_scan2(const int* __restrict__ bsum,
                                               int* __restrict__ boff) {
  __shared__ int s[256];
  const int t = threadIdx.x;
  int v = (t < 196) ? bsum[t] : 0;
  s[t] = v;
  __syncthreads();
  int x = v;
  for (int off = 1; off < 256; off <<= 1) {
    int y = (t >= off) ? s[t - off] : 0;
    __syncthreads();
    x += y;
    s[t] = x;
    __syncthreads();
  }
  if (t < 196) boff[t] = x - v;
}

__global__ void k_scan3(const int* __restrict__ excl, const int* __restrict__ boff,
                        int* __restrict__ rowptr, int* __restrict__ cursor) {
  int i = blockIdx.x * 256 + threadIdx.x;
  if (i < N_NODES) {
    int v = excl[i] + boff[blockIdx.x];
    rowptr[i] = v;
    cursor[i] = v;
  }
}

__global__ void k_scatter(const int* __restrict__ tgt, const int* __restrict__ src,
                          int* __restrict__ cursor, int* __restrict__ sortedSrc) {
  int e = blockIdx.x * 256 + threadIdx.x;
  if (e < N_EDGES) {
    int tg = tgt[e];
    int pos = atomicAdd(&cursor[tg], 1);
    sortedSrc[pos] = src[e];
  }
}

// ---------------- fused: wave-per-node softmax-agg + skip + ELU + LN + mean + Wout + ELU
// Lane l owns cols 4l..4l+3 (head = l>>3). One fp8 dword gather per lane per
// edge = coalesced 256B row. No LDS, no syncthreads; shuffles only.
__global__ __launch_bounds__(256) void k_fused(
    const u8* __restrict__ Hq, const u16* __restrict__ Hb,
    const float* __restrict__ si, const float* __restrict__ sj,
    const float* __restrict__ ba, const float* __restrict__ gamma,
    const float* __restrict__ beta, const float* __restrict__ Wout,
    const float* __restrict__ bout, const int* __restrict__ rowptr,
    const int* __restrict__ cnt, const int* __restrict__ sortedSrc,
    float* __restrict__ out) {
  const int n = blockIdx.x * 4 + (threadIdx.x >> 6);
  if (n >= N_NODES) return;
  const int l = threadIdx.x & 63;
  const int h = l >> 3;
  const int start = rowptr[n];
  const int deg = cnt[n];
  const float sb = si[n * HEADS + h] + ba[h];

  float a0 = 0.f, a1 = 0.f, a2 = 0.f, a3 = 0.f, den = 0.f;
  for (int i = 0; i < deg; i += 4) {
    int sidx[4];
#pragma unroll
    for (int k = 0; k < 4; k++)
      sidx[k] = (i + k < deg) ? sortedSrc[start + i + k] : -1;
    float ex[4];
    u32 q[4];
#pragma unroll
    for (int k = 0; k < 4; k++) {
      int s = (sidx[k] >= 0) ? sidx[k] : 0;
      float e = sb + sj[s * HEADS + h];
      e = (e >= 0.f) ? e : 0.2f * e;
      ex[k] = (sidx[k] >= 0) ? __expf(e) : 0.f;
      q[k] = *(const u32*)(Hq + (size_t)s * 256 + 4 * l);
    }
#pragma unroll
    for (int k = 0; k < 4; k++) {
      f2v lo = __builtin_amdgcn_cvt_pk_f32_fp8(q[k], false);
      f2v hi = __builtin_amdgcn_cvt_pk_f32_fp8(q[k], true);
      a0 += ex[k] * lo.x;
      a1 += ex[k] * lo.y;
      a2 += ex[k] * hi.x;
      a3 += ex[k] * hi.y;
      den += ex[k];
    }
  }
  const float inv = (deg > 0) ? 1.f / den : 0.f;

  // skip connection from bf16 H
  const u32* hp = (const u32*)(Hb + (size_t)n * HID + 4 * l);
  u32 h01 = hp[0], h23 = hp[1];
  float v0 = a0 * inv + bf2f((u16)h01);
  float v1 = a1 * inv + bf2f((u16)(h01 >> 16));
  float v2 = a2 * inv + bf2f((u16)h23);
  float v3 = a3 * inv + bf2f((u16)(h23 >> 16));
  // ELU
  v0 = (v0 > 0.f) ? v0 : expm1f(v0);
  v1 = (v1 > 0.f) ? v1 : expm1f(v1);
  v2 = (v2 > 0.f) ? v2 : expm1f(v2);
  v3 = (v3 > 0.f) ? v3 : expm1f(v3);

  // LayerNorm over this head's 32 cols = 8 lanes x 4 cols
  float sum = v0 + v1 + v2 + v3;
  float sq = v0 * v0 + v1 * v1 + v2 * v2 + v3 * v3;
#pragma unroll
  for (int off = 1; off <= 4; off <<= 1) {
    sum += __shfl_xor(sum, off);
    sq  += __shfl_xor(sq, off);
  }
  float mu = sum * (1.f / 32.f);
  float var = sq * (1.f / 32.f) - mu * mu;
  float rs = rsqrtf(var + 1e-5f);
  float4 gm = *(const float4*)&gamma[4 * l];
  float4 bt = *(const float4*)&beta[4 * l];
  float m0 = (v0 - mu) * rs * gm.x + bt.x;
  float m1 = (v1 - mu) * rs * gm.y + bt.y;
  float m2 = (v2 - mu) * rs * gm.z + bt.z;
  float m3 = (v3 - mu) * rs * gm.w + bt.w;

  // head-mean: reduce across the 8 head groups (stride-8 lanes), all lanes get sum
#pragma unroll
  for (int off = 8; off <= 32; off <<= 1) {
    m0 += __shfl_xor(m0, off);
    m1 += __shfl_xor(m1, off);
    m2 += __shfl_xor(m2, off);
    m3 += __shfl_xor(m3, off);
  }
  float mv[4] = {m0 * 0.125f, m1 * 0.125f, m2 * 0.125f, m3 * 0.125f};
  // lanes 0..7 hold meanv[d] for d = 4*lane .. 4*lane+3 (replicated across groups)

  // y[c] = bout[c] + sum_k meanv[k] * Wout[k][c], c = 4l..4l+3
  float4 y = *(const float4*)&bout[4 * l];
#pragma unroll
  for (int k = 0; k < 32; k++) {
    float mk = __shfl(mv[k & 3], k >> 2);   // broadcast from lane k/4 -> readlane
    float4 wv = *(const float4*)&Wout[k * HID + 4 * l];
    y.x += mk * wv.x;
    y.y += mk * wv.y;
    y.z += mk * wv.z;
    y.w += mk * wv.w;
  }
  y.x = (y.x > 0.f) ? y.x : expm1f(y.x);
  y.y = (y.y > 0.f) ? y.y : expm1f(y.y);
  y.z = (y.z > 0.f) ? y.z : expm1f(y.z);
  y.w = (y.w > 0.f) ? y.w : expm1f(y.w);
  *(float4*)&out[(size_t)n * HID + 4 * l] = y;
}

extern "C" void kernel_launch(void* const* d_in, const int* in_sizes, int n_in,
                              void* d_out, int out_size, void* d_ws, size_t ws_size,
                              hipStream_t stream) {
  const float* X     = (const float*)d_in[0];
  const int*   EI    = (const int*)d_in[1];
  const float* W     = (const float*)d_in[2];
  const float* bw    = (const float*)d_in[3];
  const float* A     = (const float*)d_in[4];
  const float* ba    = (const float*)d_in[5];
  const float* gamma = (const float*)d_in[6];
  const float* beta  = (const float*)d_in[7];
  const float* Wout  = (const float*)d_in[8];
  const float* bout  = (const float*)d_in[9];
  float* out = (float*)d_out;
  const int* tgt = EI;
  const int* src = EI + N_EDGES;

  char* ws = (char*)d_ws;
  size_t off = 0;
  auto alloc = [&](size_t bytes) -> void* {
    void* p = ws + off;
    off += bytes;
    off = (off + 255) & ~(size_t)255;
    return p;
  };
  u16*   Hb        = (u16*)  alloc((size_t)N_NODES * HID * 2);
  u8*    Hq        = (u8*)   alloc((size_t)N_NODES * HID);
  u16*   Wt_g      = (u16*)  alloc((size_t)HID * FIN * 2);
  float* si        = (float*)alloc((size_t)N_NODES * HEADS * 4);
  float* sj        = (float*)alloc((size_t)N_NODES * HEADS * 4);
  int*   cnt       = (int*)  alloc((size_t)N_NODES * 4);
  int*   excl      = (int*)  alloc((size_t)N_NODES * 4);
  int*   bsum      = (int*)  alloc(256 * 4);
  int*   boff      = (int*)  alloc(256 * 4);
  int*   rowptr    = (int*)  alloc((size_t)N_NODES * 4);
  int*   cursor    = (int*)  alloc((size_t)N_NODES * 4);
  int*   sortedSrc = (int*)  alloc((size_t)N_EDGES * 4);

  hipMemsetAsync(cnt, 0, (size_t)N_NODES * 4, stream);
  k_hist<<<(N_EDGES + 255) / 256, 256, 0, stream>>>(tgt, cnt);
  k_scan1<<<196, 256, 0, stream>>>(cnt, excl, bsum);
  k_scan2<<<1, 256, 0, stream>>>(bsum, boff);
  k_scan3<<<196, 256, 0, stream>>>(excl, boff, rowptr, cursor);
  k_scatter<<<(N_EDGES + 255) / 256, 256, 0, stream>>>(tgt, src, cursor, sortedSrc);
  k_wprep<<<64, 256, 0, stream>>>(W, Wt_g);
  k_gemm<<<((N_NODES + 127) / 128) * 2, 256, 0, stream>>>(X, Wt_g, bw, A, Hb, si, sj);
  k_cvt<<<(N_NODES * HID / 8 + 255) / 256, 256, 0, stream>>>(Hb, Hq);
  k_fused<<<(N_NODES + 3) / 4, 256, 0, stream>>>(Hq, Hb, si, sj, ba, gamma, beta,
                                                 Wout, bout, rowptr, cnt, sortedSrc, out);
}